// Round 1
// baseline (2402.052 us; speedup 1.0000x reference)
//
#include <hip/hip_runtime.h>

#define N_NODES 100000
#define N_EDGES 600000
#define K_DIM 128

// ---------------- degree: deg[dst] += 1 ----------------
__global__ __launch_bounds__(256) void deg_kernel(const int* __restrict__ dst,
                                                  float* __restrict__ deg, int nE) {
  int i = blockIdx.x * blockDim.x + threadIdx.x;
  if (i < nE) atomicAdd(&deg[dst[i]], 1.0f);
}

// ---------------- scatter: agg[dst] += H[src], 32 threads/edge, float4 ----------------
__global__ __launch_bounds__(256) void scatter_kernel(const float* __restrict__ H,
                                                      const int* __restrict__ src,
                                                      const int* __restrict__ dst,
                                                      float* __restrict__ agg, int nE) {
  int t = blockIdx.x * blockDim.x + threadIdx.x;
  int e = t >> 5;           // 32 threads per edge
  int c = (t & 31) << 2;    // 4 consecutive floats per thread
  if (e >= nE) return;
  int s = src[e];
  int d = dst[e];
  float4 v = *(const float4*)(H + (size_t)s * K_DIM + c);
  float* out = agg + (size_t)d * K_DIM + c;
  atomicAdd(out + 0, v.x);
  atomicAdd(out + 1, v.y);
  atomicAdd(out + 2, v.z);
  atomicAdd(out + 3, v.w);
}

// ---------------- fused SAGE gemm: OUT = act(X@Wself + (AGG/deg)@Wneigh + b) ----------------
// Block = 256 threads. Each thread computes a 4-row x 4-col register tile.
// X and AGG tiles staged in LDS (row-major, stride 128); W read from L2.
template <int M, int DO_RELU>
__global__ __launch_bounds__(256) void sage_gemm(const float* __restrict__ X,
                                                 const float* __restrict__ AGG,
                                                 const float* __restrict__ deg,
                                                 const float* __restrict__ Wself,
                                                 const float* __restrict__ Wneigh,
                                                 const float* __restrict__ bias,
                                                 float* __restrict__ OUT, int N) {
  constexpr int K = K_DIM;
  constexpr int COLG = M / 4;          // col groups of 4
  constexpr int ROWG = 256 / COLG;     // row groups
  constexpr int TILE_R = ROWG * 4;     // rows per block tile
  __shared__ float xs[TILE_R * K];
  __shared__ float as[TILE_R * K];

  const int tid = threadIdx.x;
  const int cg = tid % COLG;
  const int rg = tid / COLG;

  for (int row0 = blockIdx.x * TILE_R; row0 < N; row0 += gridDim.x * TILE_R) {
    __syncthreads();  // protect LDS from previous iteration's readers
    // cooperative tile load: TILE_R rows x 128 cols in float4 units
    constexpr int NVEC = TILE_R * (K / 4);
    for (int v = tid; v < NVEC; v += 256) {
      int r = v / (K / 4);
      int c = (v % (K / 4)) * 4;
      int grow = row0 + r;
      float4 xv = make_float4(0.f, 0.f, 0.f, 0.f);
      float4 av = make_float4(0.f, 0.f, 0.f, 0.f);
      if (grow < N) {
        xv = *(const float4*)(X + (size_t)grow * K + c);
        av = *(const float4*)(AGG + (size_t)grow * K + c);
        float inv = 1.0f / fmaxf(deg[grow], 1.0f);
        av.x *= inv; av.y *= inv; av.z *= inv; av.w *= inv;
      }
      *(float4*)(xs + r * K + c) = xv;
      *(float4*)(as + r * K + c) = av;
    }
    __syncthreads();

    float acc[4][4];
#pragma unroll
    for (int r = 0; r < 4; ++r)
#pragma unroll
      for (int c = 0; c < 4; ++c) acc[r][c] = 0.f;

    const float* xrow = xs + (rg * 4) * K;
    const float* arow = as + (rg * 4) * K;
    const float* wsp = Wself + cg * 4;
    const float* wnp = Wneigh + cg * 4;
#pragma unroll 4
    for (int k = 0; k < K; ++k) {
      float4 wv = *(const float4*)(wsp + (size_t)k * M);
      float4 nv = *(const float4*)(wnp + (size_t)k * M);
#pragma unroll
      for (int r = 0; r < 4; ++r) {
        float xv = xrow[r * K + k];
        float av = arow[r * K + k];
        acc[r][0] += xv * wv.x; acc[r][0] += av * nv.x;
        acc[r][1] += xv * wv.y; acc[r][1] += av * nv.y;
        acc[r][2] += xv * wv.z; acc[r][2] += av * nv.z;
        acc[r][3] += xv * wv.w; acc[r][3] += av * nv.w;
      }
    }

    float4 bv = *(const float4*)(bias + cg * 4);
#pragma unroll
    for (int r = 0; r < 4; ++r) {
      int grow = row0 + rg * 4 + r;
      if (grow < N) {
        float4 o;
        o.x = acc[r][0] + bv.x;
        o.y = acc[r][1] + bv.y;
        o.z = acc[r][2] + bv.z;
        o.w = acc[r][3] + bv.w;
        if (DO_RELU) {
          o.x = fmaxf(o.x, 0.f); o.y = fmaxf(o.y, 0.f);
          o.z = fmaxf(o.z, 0.f); o.w = fmaxf(o.w, 0.f);
        }
        *(float4*)(OUT + (size_t)grow * M + cg * 4) = o;
      }
    }
  }
}

extern "C" void kernel_launch(void* const* d_in, const int* in_sizes, int n_in,
                              void* d_out, int out_size, void* d_ws, size_t ws_size,
                              hipStream_t stream) {
  const float* x   = (const float*)d_in[0];
  const int*   src = (const int*)d_in[1];
  const int*   dst = (const int*)d_in[2];
  const float* Ws1 = (const float*)d_in[3];
  const float* Wn1 = (const float*)d_in[4];
  const float* b1  = (const float*)d_in[5];
  const float* Ws2 = (const float*)d_in[6];
  const float* Wn2 = (const float*)d_in[7];
  const float* b2  = (const float*)d_in[8];
  float* out = (float*)d_out;

  char* ws = (char*)d_ws;
  float* deg = (float*)ws;  // N floats
  size_t off1 = ((size_t)N_NODES * 4 + 4095) & ~(size_t)4095;
  float* agg = (float*)(ws + off1);  // N*128 floats (reused by both layers)
  size_t aggBytes = (size_t)N_NODES * K_DIM * 4;
  size_t off2 = off1 + ((aggBytes + 4095) & ~(size_t)4095);
  float* h1 = (float*)(ws + off2);  // N*128 floats

  hipMemsetAsync(deg, 0, (size_t)N_NODES * 4, stream);
  hipMemsetAsync(agg, 0, aggBytes, stream);

  deg_kernel<<<(N_EDGES + 255) / 256, 256, 0, stream>>>(dst, deg, N_EDGES);

  // layer 1 aggregation + gemm
  {
    long long t = (long long)N_EDGES * 32;
    scatter_kernel<<<(int)((t + 255) / 256), 256, 0, stream>>>(x, src, dst, agg, N_EDGES);
  }
  sage_gemm<128, 1><<<(N_NODES + 31) / 32, 256, 0, stream>>>(x, agg, deg, Ws1, Wn1, b1, h1, N_NODES);

  // layer 2 aggregation + gemm
  hipMemsetAsync(agg, 0, aggBytes, stream);
  {
    long long t = (long long)N_EDGES * 32;
    scatter_kernel<<<(int)((t + 255) / 256), 256, 0, stream>>>(h1, src, dst, agg, N_EDGES);
  }
  sage_gemm<64, 0><<<(N_NODES + 63) / 64, 256, 0, stream>>>(h1, agg, deg, Ws2, Wn2, b2, out, N_NODES);
}

// Round 2
// 427.277 us; speedup vs baseline: 5.6218x; 5.6218x over previous
//
#include <hip/hip_runtime.h>

#define N_NODES 100000
#define N_EDGES 600000
#define K_DIM 128
#define M2 64
#define SCAN_BLOCKS ((N_NODES + 255) / 256)   // 391

// ---------------- degree count (int) ----------------
__global__ __launch_bounds__(256) void deg_count(const int* __restrict__ dst,
                                                 int* __restrict__ deg, int nE) {
  int i = blockIdx.x * blockDim.x + threadIdx.x;
  if (i < nE) atomicAdd(&deg[dst[i]], 1);
}

// ---------------- hierarchical exclusive scan ----------------
__global__ __launch_bounds__(256) void scan1(const int* __restrict__ deg,
                                             int* __restrict__ partial,
                                             int* __restrict__ blockSums, int n) {
  __shared__ int sdata[256];
  int tid = threadIdx.x;
  int i = blockIdx.x * 256 + tid;
  int v = (i < n) ? deg[i] : 0;
  sdata[tid] = v;
  __syncthreads();
#pragma unroll
  for (int off = 1; off < 256; off <<= 1) {
    int t = (tid >= off) ? sdata[tid - off] : 0;
    __syncthreads();
    sdata[tid] += t;
    __syncthreads();
  }
  if (i < n) partial[i] = sdata[tid] - v;  // exclusive within block
  if (tid == 255) blockSums[blockIdx.x] = sdata[255];
}

__global__ __launch_bounds__(512) void scan2(int* __restrict__ blockSums, int nb) {
  __shared__ int sdata[512];
  int tid = threadIdx.x;
  int v = (tid < nb) ? blockSums[tid] : 0;
  sdata[tid] = v;
  __syncthreads();
#pragma unroll
  for (int off = 1; off < 512; off <<= 1) {
    int t = (tid >= off) ? sdata[tid - off] : 0;
    __syncthreads();
    sdata[tid] += t;
    __syncthreads();
  }
  if (tid < nb) blockSums[tid] = sdata[tid] - v;  // exclusive
}

__global__ __launch_bounds__(256) void scan3(int* __restrict__ row_ptr,
                                             const int* __restrict__ blockSums,
                                             int* __restrict__ cursor, int n, int nE) {
  int i = blockIdx.x * 256 + threadIdx.x;
  if (i < n) {
    int val = row_ptr[i] + blockSums[i >> 8];
    row_ptr[i] = val;
    cursor[i] = val;
  }
  if (i == 0) row_ptr[n] = nE;
}

// ---------------- CSR fill: one cursor atomic per edge ----------------
__global__ __launch_bounds__(256) void csr_fill(const int* __restrict__ src,
                                                const int* __restrict__ dst,
                                                int* __restrict__ cursor,
                                                int* __restrict__ csr_src, int nE) {
  int e = blockIdx.x * blockDim.x + threadIdx.x;
  if (e < nE) {
    int pos = atomicAdd(&cursor[dst[e]], 1);
    csr_src[pos] = src[e];
  }
}

// ---------------- gather-mean, 128-wide: agg[n] = mean_{e in CSR[n]} X[src] ----------------
__global__ __launch_bounds__(256) void aggregate128(const float* __restrict__ X,
                                                    const int* __restrict__ row_ptr,
                                                    const int* __restrict__ csr_src,
                                                    float* __restrict__ agg, int n) {
  int t = blockIdx.x * blockDim.x + threadIdx.x;
  int node = t >> 5;
  int c = (t & 31) << 2;
  if (node >= n) return;
  int beg = row_ptr[node], end = row_ptr[node + 1];
  float4 acc = make_float4(0.f, 0.f, 0.f, 0.f);
  for (int e = beg; e < end; ++e) {
    int s = csr_src[e];
    float4 v = *(const float4*)(X + (size_t)s * K_DIM + c);
    acc.x += v.x; acc.y += v.y; acc.z += v.z; acc.w += v.w;
  }
  float inv = 1.0f / (float)max(end - beg, 1);
  acc.x *= inv; acc.y *= inv; acc.z *= inv; acc.w *= inv;
  *(float4*)(agg + (size_t)node * K_DIM + c) = acc;
}

// ---------------- gather-mean-add, 64-wide: out[n] += mean g[src] ----------------
__global__ __launch_bounds__(256) void aggregate64_add(const float* __restrict__ g,
                                                       const int* __restrict__ row_ptr,
                                                       const int* __restrict__ csr_src,
                                                       float* __restrict__ out, int n) {
  int t = blockIdx.x * blockDim.x + threadIdx.x;
  int node = t >> 4;
  int c = (t & 15) << 2;
  if (node >= n) return;
  int beg = row_ptr[node], end = row_ptr[node + 1];
  float4 acc = make_float4(0.f, 0.f, 0.f, 0.f);
  for (int e = beg; e < end; ++e) {
    int s = csr_src[e];
    float4 v = *(const float4*)(g + (size_t)s * M2 + c);
    acc.x += v.x; acc.y += v.y; acc.z += v.z; acc.w += v.w;
  }
  float inv = 1.0f / (float)max(end - beg, 1);
  float4 o = *(const float4*)(out + (size_t)node * M2 + c);
  o.x += acc.x * inv; o.y += acc.y * inv; o.z += acc.z * inv; o.w += acc.w * inv;
  *(float4*)(out + (size_t)node * M2 + c) = o;
}

// ---------------- layer-1 fused GEMM: h1 = relu(X@Ws + AGG@Wn + b) ----------------
// AGG is already the neighbor mean. M=128: 32 col-groups, 8 row-groups, 32-row tile.
__global__ __launch_bounds__(256) void gemm1(const float* __restrict__ X,
                                             const float* __restrict__ AGG,
                                             const float* __restrict__ Wself,
                                             const float* __restrict__ Wneigh,
                                             const float* __restrict__ bias,
                                             float* __restrict__ OUT, int N) {
  constexpr int K = K_DIM;
  constexpr int M = 128;
  constexpr int COLG = M / 4;       // 32
  constexpr int ROWG = 256 / COLG;  // 8
  constexpr int TILE_R = ROWG * 4;  // 32
  __shared__ float xs[TILE_R * K];
  __shared__ float as[TILE_R * K];

  const int tid = threadIdx.x;
  const int cg = tid % COLG;
  const int rg = tid / COLG;

  int row0 = blockIdx.x * TILE_R;
  if (row0 >= N) return;

  constexpr int NVEC = TILE_R * (K / 4);
  for (int v = tid; v < NVEC; v += 256) {
    int r = v / (K / 4);
    int c = (v % (K / 4)) * 4;
    int grow = row0 + r;
    float4 xv = make_float4(0.f, 0.f, 0.f, 0.f);
    float4 av = make_float4(0.f, 0.f, 0.f, 0.f);
    if (grow < N) {
      xv = *(const float4*)(X + (size_t)grow * K + c);
      av = *(const float4*)(AGG + (size_t)grow * K + c);
    }
    *(float4*)(xs + r * K + c) = xv;
    *(float4*)(as + r * K + c) = av;
  }
  __syncthreads();

  float acc[4][4];
#pragma unroll
  for (int r = 0; r < 4; ++r)
#pragma unroll
    for (int c = 0; c < 4; ++c) acc[r][c] = 0.f;

  const float* xrow = xs + (rg * 4) * K;
  const float* arow = as + (rg * 4) * K;
  const float* wsp = Wself + cg * 4;
  const float* wnp = Wneigh + cg * 4;
#pragma unroll 4
  for (int k = 0; k < K; ++k) {
    float4 wv = *(const float4*)(wsp + (size_t)k * M);
    float4 nv = *(const float4*)(wnp + (size_t)k * M);
#pragma unroll
    for (int r = 0; r < 4; ++r) {
      float xv = xrow[r * K + k];
      float av = arow[r * K + k];
      acc[r][0] += xv * wv.x; acc[r][0] += av * nv.x;
      acc[r][1] += xv * wv.y; acc[r][1] += av * nv.y;
      acc[r][2] += xv * wv.z; acc[r][2] += av * nv.z;
      acc[r][3] += xv * wv.w; acc[r][3] += av * nv.w;
    }
  }

  float4 bv = *(const float4*)(bias + cg * 4);
#pragma unroll
  for (int r = 0; r < 4; ++r) {
    int grow = row0 + rg * 4 + r;
    if (grow < N) {
      float4 o;
      o.x = fmaxf(acc[r][0] + bv.x, 0.f);
      o.y = fmaxf(acc[r][1] + bv.y, 0.f);
      o.z = fmaxf(acc[r][2] + bv.z, 0.f);
      o.w = fmaxf(acc[r][3] + bv.w, 0.f);
      *(float4*)(OUT + (size_t)grow * M + cg * 4) = o;
    }
  }
}

// ---------------- layer-2 dual GEMM: s = H@Ws + b (-> out), g = H@Wn (-> gbuf) ----------------
// M=64: 16 col-groups, 16 row-groups, 64-row tile.
__global__ __launch_bounds__(256) void gemm2_dual(const float* __restrict__ H,
                                                  const float* __restrict__ Wself,
                                                  const float* __restrict__ Wneigh,
                                                  const float* __restrict__ bias,
                                                  float* __restrict__ sOut,
                                                  float* __restrict__ gOut, int N) {
  constexpr int K = K_DIM;
  constexpr int M = M2;
  constexpr int COLG = M / 4;       // 16
  constexpr int ROWG = 256 / COLG;  // 16
  constexpr int TILE_R = ROWG * 4;  // 64
  __shared__ float xs[TILE_R * K];  // 32 KB

  const int tid = threadIdx.x;
  const int cg = tid % COLG;
  const int rg = tid / COLG;

  int row0 = blockIdx.x * TILE_R;
  if (row0 >= N) return;

  constexpr int NVEC = TILE_R * (K / 4);
  for (int v = tid; v < NVEC; v += 256) {
    int r = v / (K / 4);
    int c = (v % (K / 4)) * 4;
    int grow = row0 + r;
    float4 xv = make_float4(0.f, 0.f, 0.f, 0.f);
    if (grow < N) xv = *(const float4*)(H + (size_t)grow * K + c);
    *(float4*)(xs + r * K + c) = xv;
  }
  __syncthreads();

  float accS[4][4], accG[4][4];
#pragma unroll
  for (int r = 0; r < 4; ++r)
#pragma unroll
    for (int c = 0; c < 4; ++c) { accS[r][c] = 0.f; accG[r][c] = 0.f; }

  const float* xrow = xs + (rg * 4) * K;
  const float* wsp = Wself + cg * 4;
  const float* wnp = Wneigh + cg * 4;
#pragma unroll 4
  for (int k = 0; k < K; ++k) {
    float4 wv = *(const float4*)(wsp + (size_t)k * M);
    float4 nv = *(const float4*)(wnp + (size_t)k * M);
#pragma unroll
    for (int r = 0; r < 4; ++r) {
      float xv = xrow[r * K + k];
      accS[r][0] += xv * wv.x; accG[r][0] += xv * nv.x;
      accS[r][1] += xv * wv.y; accG[r][1] += xv * nv.y;
      accS[r][2] += xv * wv.z; accG[r][2] += xv * nv.z;
      accS[r][3] += xv * wv.w; accG[r][3] += xv * nv.w;
    }
  }

  float4 bv = *(const float4*)(bias + cg * 4);
#pragma unroll
  for (int r = 0; r < 4; ++r) {
    int grow = row0 + rg * 4 + r;
    if (grow < N) {
      float4 s, g;
      s.x = accS[r][0] + bv.x; g.x = accG[r][0];
      s.y = accS[r][1] + bv.y; g.y = accG[r][1];
      s.z = accS[r][2] + bv.z; g.z = accG[r][2];
      s.w = accS[r][3] + bv.w; g.w = accG[r][3];
      *(float4*)(sOut + (size_t)grow * M + cg * 4) = s;
      *(float4*)(gOut + (size_t)grow * M + cg * 4) = g;
    }
  }
}

extern "C" void kernel_launch(void* const* d_in, const int* in_sizes, int n_in,
                              void* d_out, int out_size, void* d_ws, size_t ws_size,
                              hipStream_t stream) {
  const float* x   = (const float*)d_in[0];
  const int*   src = (const int*)d_in[1];
  const int*   dst = (const int*)d_in[2];
  const float* Ws1 = (const float*)d_in[3];
  const float* Wn1 = (const float*)d_in[4];
  const float* b1  = (const float*)d_in[5];
  const float* Ws2 = (const float*)d_in[6];
  const float* Wn2 = (const float*)d_in[7];
  const float* b2  = (const float*)d_in[8];
  float* out = (float*)d_out;

  char* ws = (char*)d_ws;
  size_t off = 0;
  auto alloc = [&](size_t bytes) {
    void* p = ws + off;
    off = (off + bytes + 4095) & ~(size_t)4095;
    return p;
  };
  int* deg       = (int*)alloc((size_t)N_NODES * 4);
  int* row_ptr   = (int*)alloc((size_t)(N_NODES + 1) * 4);
  int* cursor    = (int*)alloc((size_t)N_NODES * 4);
  int* blockSums = (int*)alloc(512 * 4);
  int* csr_src   = (int*)alloc((size_t)N_EDGES * 4);
  float* agg     = (float*)alloc((size_t)N_NODES * K_DIM * 4);  // reused as g (N*64)
  float* h1      = (float*)alloc((size_t)N_NODES * K_DIM * 4);
  float* g       = agg;

  hipMemsetAsync(deg, 0, (size_t)N_NODES * 4, stream);

  // ---- CSR build ----
  deg_count<<<(N_EDGES + 255) / 256, 256, 0, stream>>>(dst, deg, N_EDGES);
  scan1<<<SCAN_BLOCKS, 256, 0, stream>>>(deg, row_ptr, blockSums, N_NODES);
  scan2<<<1, 512, 0, stream>>>(blockSums, SCAN_BLOCKS);
  scan3<<<SCAN_BLOCKS, 256, 0, stream>>>(row_ptr, blockSums, cursor, N_NODES, N_EDGES);
  csr_fill<<<(N_EDGES + 255) / 256, 256, 0, stream>>>(src, dst, cursor, csr_src, N_EDGES);

  // ---- layer 1: gather-mean + fused GEMM ----
  {
    long long t = (long long)N_NODES * 32;
    aggregate128<<<(int)((t + 255) / 256), 256, 0, stream>>>(x, row_ptr, csr_src, agg, N_NODES);
  }
  gemm1<<<(N_NODES + 31) / 32, 256, 0, stream>>>(x, agg, Ws1, Wn1, b1, h1, N_NODES);

  // ---- layer 2: dual GEMM, then 64-wide gather-mean-add into out ----
  gemm2_dual<<<(N_NODES + 63) / 64, 256, 0, stream>>>(h1, Ws2, Wn2, b2, out, g, N_NODES);
  {
    long long t = (long long)N_NODES * 16;
    aggregate64_add<<<(int)((t + 255) / 256), 256, 0, stream>>>(g, row_ptr, csr_src, out, N_NODES);
  }
}

// Round 3
// 342.650 us; speedup vs baseline: 7.0102x; 1.2470x over previous
//
#include <hip/hip_runtime.h>

#define N_NODES 100000
#define N_EDGES 600000
#define K_DIM 128
#define M2 64
#define SCAN_BLOCKS ((N_NODES + 255) / 256)   // 391

using frag_ab = __attribute__((ext_vector_type(8))) short;   // 8 bf16 = 4 VGPRs
using frag_cd = __attribute__((ext_vector_type(4))) float;   // 4 fp32 acc

// fp32 -> bf16 round-to-nearest-even
__device__ __forceinline__ unsigned short f2b(float f) {
  unsigned u = __builtin_bit_cast(unsigned, f);
  u = (u + 0x7fffu + ((u >> 16) & 1u)) >> 16;
  return (unsigned short)u;
}
__device__ __forceinline__ float b2f(unsigned short b) {
  unsigned u = ((unsigned)b) << 16;
  return __builtin_bit_cast(float, u);
}

// ---------------- convert x to bf16 ----------------
__global__ __launch_bounds__(256) void conv_x_kernel(const float* __restrict__ x,
                                                     unsigned short* __restrict__ xb,
                                                     long n4) {
  long i = (long)blockIdx.x * blockDim.x + threadIdx.x;
  if (i >= n4) return;
  float4 v = *(const float4*)(x + i * 4);
  ushort4 o;
  o.x = f2b(v.x); o.y = f2b(v.y); o.z = f2b(v.z); o.w = f2b(v.w);
  *(ushort4*)(xb + i * 4) = o;
}

// ---------------- convert + transpose weights: WT[n][k] = W[k][n], bf16 ----------------
// blockIdx.y selects matrix: 0=Ws1(M=128),1=Wn1(128),2=Ws2(64),3=Wn2(64)
__global__ __launch_bounds__(256) void conv_wt_kernel(const float* __restrict__ Ws1,
                                                      const float* __restrict__ Wn1,
                                                      const float* __restrict__ Ws2,
                                                      const float* __restrict__ Wn2,
                                                      unsigned short* __restrict__ Ws1T,
                                                      unsigned short* __restrict__ Wn1T,
                                                      unsigned short* __restrict__ Ws2T,
                                                      unsigned short* __restrict__ Wn2T) {
  int which = blockIdx.y;
  const float* W = (which == 0) ? Ws1 : (which == 1) ? Wn1 : (which == 2) ? Ws2 : Wn2;
  unsigned short* WT = (which == 0) ? Ws1T : (which == 1) ? Wn1T : (which == 2) ? Ws2T : Wn2T;
  int M = (which < 2) ? 128 : 64;
  int i = blockIdx.x * 256 + threadIdx.x;  // i = n*128 + k
  if (i >= M * 128) return;
  int n = i >> 7, k = i & 127;
  WT[i] = f2b(W[k * M + n]);
}

// ---------------- degree count ----------------
__global__ __launch_bounds__(256) void deg_count(const int* __restrict__ dst,
                                                 int* __restrict__ deg, int nE) {
  int i = blockIdx.x * blockDim.x + threadIdx.x;
  if (i < nE) atomicAdd(&deg[dst[i]], 1);
}

// ---------------- hierarchical exclusive scan ----------------
__global__ __launch_bounds__(256) void scan1(const int* __restrict__ deg,
                                             int* __restrict__ partial,
                                             int* __restrict__ blockSums, int n) {
  __shared__ int sdata[256];
  int tid = threadIdx.x;
  int i = blockIdx.x * 256 + tid;
  int v = (i < n) ? deg[i] : 0;
  sdata[tid] = v;
  __syncthreads();
#pragma unroll
  for (int off = 1; off < 256; off <<= 1) {
    int t = (tid >= off) ? sdata[tid - off] : 0;
    __syncthreads();
    sdata[tid] += t;
    __syncthreads();
  }
  if (i < n) partial[i] = sdata[tid] - v;
  if (tid == 255) blockSums[blockIdx.x] = sdata[255];
}

__global__ __launch_bounds__(512) void scan2(int* __restrict__ blockSums, int nb) {
  __shared__ int sdata[512];
  int tid = threadIdx.x;
  int v = (tid < nb) ? blockSums[tid] : 0;
  sdata[tid] = v;
  __syncthreads();
#pragma unroll
  for (int off = 1; off < 512; off <<= 1) {
    int t = (tid >= off) ? sdata[tid - off] : 0;
    __syncthreads();
    sdata[tid] += t;
    __syncthreads();
  }
  if (tid < nb) blockSums[tid] = sdata[tid] - v;
}

__global__ __launch_bounds__(256) void scan3(int* __restrict__ row_ptr,
                                             const int* __restrict__ blockSums,
                                             int* __restrict__ cursor, int n, int nE) {
  int i = blockIdx.x * 256 + threadIdx.x;
  if (i < n) {
    int val = row_ptr[i] + blockSums[i >> 8];
    row_ptr[i] = val;
    cursor[i] = val;
  }
  if (i == 0) row_ptr[n] = nE;
}

// ---------------- CSR fill ----------------
__global__ __launch_bounds__(256) void csr_fill(const int* __restrict__ src,
                                                const int* __restrict__ dst,
                                                int* __restrict__ cursor,
                                                int* __restrict__ csr_src, int nE) {
  int e = blockIdx.x * blockDim.x + threadIdx.x;
  if (e < nE) {
    int pos = atomicAdd(&cursor[dst[e]], 1);
    csr_src[pos] = src[e];
  }
}

// ---------------- gather-mean, 128 bf16 cols: 16 threads/node ----------------
__global__ __launch_bounds__(256) void aggregate128(const unsigned short* __restrict__ xb,
                                                    const int* __restrict__ row_ptr,
                                                    const int* __restrict__ csr_src,
                                                    unsigned short* __restrict__ agg, int n) {
  int t = blockIdx.x * blockDim.x + threadIdx.x;
  int node = t >> 4;
  int c = (t & 15) << 3;  // 8 bf16 per thread
  if (node >= n) return;
  int beg = row_ptr[node], end = row_ptr[node + 1];
  float acc[8];
#pragma unroll
  for (int j = 0; j < 8; ++j) acc[j] = 0.f;
  for (int e = beg; e < end; ++e) {
    int s = csr_src[e];
    uint4 v = *(const uint4*)(xb + (size_t)s * K_DIM + c);
    unsigned u[4] = {v.x, v.y, v.z, v.w};
#pragma unroll
    for (int j = 0; j < 4; ++j) {
      acc[2 * j]     += __builtin_bit_cast(float, u[j] << 16);
      acc[2 * j + 1] += __builtin_bit_cast(float, u[j] & 0xffff0000u);
    }
  }
  float inv = 1.0f / (float)max(end - beg, 1);
  uint4 o;
  unsigned* op = (unsigned*)&o;
#pragma unroll
  for (int j = 0; j < 4; ++j) {
    unsigned lo = f2b(acc[2 * j] * inv);
    unsigned hi = f2b(acc[2 * j + 1] * inv);
    op[j] = lo | (hi << 16);
  }
  *(uint4*)(agg + (size_t)node * K_DIM + c) = o;
}

// ---------------- gather-mean-add, 64 bf16 cols -> out fp32: 8 threads/node ----------------
__global__ __launch_bounds__(256) void aggregate64_add(const unsigned short* __restrict__ g,
                                                       const int* __restrict__ row_ptr,
                                                       const int* __restrict__ csr_src,
                                                       float* __restrict__ out, int n) {
  int t = blockIdx.x * blockDim.x + threadIdx.x;
  int node = t >> 3;
  int c = (t & 7) << 3;  // 8 bf16 per thread
  if (node >= n) return;
  int beg = row_ptr[node], end = row_ptr[node + 1];
  float acc[8];
#pragma unroll
  for (int j = 0; j < 8; ++j) acc[j] = 0.f;
  for (int e = beg; e < end; ++e) {
    int s = csr_src[e];
    uint4 v = *(const uint4*)(g + (size_t)s * M2 + c);
    unsigned u[4] = {v.x, v.y, v.z, v.w};
#pragma unroll
    for (int j = 0; j < 4; ++j) {
      acc[2 * j]     += __builtin_bit_cast(float, u[j] << 16);
      acc[2 * j + 1] += __builtin_bit_cast(float, u[j] & 0xffff0000u);
    }
  }
  float inv = 1.0f / (float)max(end - beg, 1);
  float* op = out + (size_t)node * M2 + c;
  float4 o0 = *(float4*)(op);
  float4 o1 = *(float4*)(op + 4);
  o0.x += acc[0] * inv; o0.y += acc[1] * inv; o0.z += acc[2] * inv; o0.w += acc[3] * inv;
  o1.x += acc[4] * inv; o1.y += acc[5] * inv; o1.z += acc[6] * inv; o1.w += acc[7] * inv;
  *(float4*)(op) = o0;
  *(float4*)(op + 4) = o1;
}

// ---------------- layer-1 MFMA GEMM: h1 = relu(xb@Ws1 + aggb@Wn1 + b1), bf16 out ----------------
// Block = 4 waves; wave w handles rows row0+w*16 .. +15, all 128 cols (8 col-tiles).
__global__ __launch_bounds__(256) void gemm1_mfma(const unsigned short* __restrict__ xb,
                                                  const unsigned short* __restrict__ aggb,
                                                  const unsigned short* __restrict__ WsT,
                                                  const unsigned short* __restrict__ WnT,
                                                  const float* __restrict__ bias,
                                                  unsigned short* __restrict__ h1, int N) {
  const int tid = threadIdx.x;
  const int wave = tid >> 6;
  const int lane = tid & 63;
  const int l15 = lane & 15;
  const int q = lane >> 4;
  const int row0 = blockIdx.x * 64 + wave * 16;

  int m = row0 + l15;
  int mc = (m < N) ? m : (N - 1);
  const unsigned short* xrow = xb + (size_t)mc * K_DIM + q * 8;
  const unsigned short* grow = aggb + (size_t)mc * K_DIM + q * 8;
  const int wtoff = l15 * K_DIM + q * 8;   // within a col-tile, tile stride = 16*128

  frag_cd acc[8];
#pragma unroll
  for (int ct = 0; ct < 8; ++ct) acc[ct] = (frag_cd)(0.f);

#pragma unroll
  for (int kb = 0; kb < 4; ++kb) {
    frag_ab ax = *(const frag_ab*)(xrow + kb * 32);
    frag_ab ag = *(const frag_ab*)(grow + kb * 32);
#pragma unroll
    for (int ct = 0; ct < 8; ++ct) {
      frag_ab bs = *(const frag_ab*)(WsT + ct * (16 * K_DIM) + wtoff + kb * 32);
      frag_ab bn = *(const frag_ab*)(WnT + ct * (16 * K_DIM) + wtoff + kb * 32);
      acc[ct] = __builtin_amdgcn_mfma_f32_16x16x32_bf16(ax, bs, acc[ct], 0, 0, 0);
      acc[ct] = __builtin_amdgcn_mfma_f32_16x16x32_bf16(ag, bn, acc[ct], 0, 0, 0);
    }
  }

  // C/D layout: col = lane&15, row = q*4 + r
#pragma unroll
  for (int ct = 0; ct < 8; ++ct) {
    int col = ct * 16 + l15;
    float bv = bias[col];
#pragma unroll
    for (int r = 0; r < 4; ++r) {
      int grow_out = row0 + q * 4 + r;
      if (grow_out < N) {
        float v = fmaxf(acc[ct][r] + bv, 0.f);
        h1[(size_t)grow_out * K_DIM + col] = f2b(v);
      }
    }
  }
}

// ---------------- layer-2 dual MFMA GEMM: s = h1@Ws2 + b2 -> out(fp32); g = h1@Wn2 -> bf16 ----------------
__global__ __launch_bounds__(256) void gemm2_mfma(const unsigned short* __restrict__ hb,
                                                  const unsigned short* __restrict__ WsT,
                                                  const unsigned short* __restrict__ WnT,
                                                  const float* __restrict__ bias,
                                                  float* __restrict__ sOut,
                                                  unsigned short* __restrict__ gOut, int N) {
  const int tid = threadIdx.x;
  const int wave = tid >> 6;
  const int lane = tid & 63;
  const int l15 = lane & 15;
  const int q = lane >> 4;
  const int row0 = blockIdx.x * 64 + wave * 16;

  int m = row0 + l15;
  int mc = (m < N) ? m : (N - 1);
  const unsigned short* hrow = hb + (size_t)mc * K_DIM + q * 8;
  const int wtoff = l15 * K_DIM + q * 8;

  frag_cd accS[4], accG[4];
#pragma unroll
  for (int ct = 0; ct < 4; ++ct) { accS[ct] = (frag_cd)(0.f); accG[ct] = (frag_cd)(0.f); }

#pragma unroll
  for (int kb = 0; kb < 4; ++kb) {
    frag_ab ah = *(const frag_ab*)(hrow + kb * 32);
#pragma unroll
    for (int ct = 0; ct < 4; ++ct) {
      frag_ab bs = *(const frag_ab*)(WsT + ct * (16 * K_DIM) + wtoff + kb * 32);
      frag_ab bn = *(const frag_ab*)(WnT + ct * (16 * K_DIM) + wtoff + kb * 32);
      accS[ct] = __builtin_amdgcn_mfma_f32_16x16x32_bf16(ah, bs, accS[ct], 0, 0, 0);
      accG[ct] = __builtin_amdgcn_mfma_f32_16x16x32_bf16(ah, bn, accG[ct], 0, 0, 0);
    }
  }

#pragma unroll
  for (int ct = 0; ct < 4; ++ct) {
    int col = ct * 16 + l15;
    float bv = bias[col];
#pragma unroll
    for (int r = 0; r < 4; ++r) {
      int grow_out = row0 + q * 4 + r;
      if (grow_out < N) {
        sOut[(size_t)grow_out * M2 + col] = accS[ct][r] + bv;
        gOut[(size_t)grow_out * M2 + col] = f2b(accG[ct][r]);
      }
    }
  }
}

extern "C" void kernel_launch(void* const* d_in, const int* in_sizes, int n_in,
                              void* d_out, int out_size, void* d_ws, size_t ws_size,
                              hipStream_t stream) {
  const float* x   = (const float*)d_in[0];
  const int*   src = (const int*)d_in[1];
  const int*   dst = (const int*)d_in[2];
  const float* Ws1 = (const float*)d_in[3];
  const float* Wn1 = (const float*)d_in[4];
  const float* b1  = (const float*)d_in[5];
  const float* Ws2 = (const float*)d_in[6];
  const float* Wn2 = (const float*)d_in[7];
  const float* b2  = (const float*)d_in[8];
  float* out = (float*)d_out;

  char* ws = (char*)d_ws;
  size_t off = 0;
  auto alloc = [&](size_t bytes) {
    void* p = ws + off;
    off = (off + bytes + 4095) & ~(size_t)4095;
    return p;
  };
  int* deg       = (int*)alloc((size_t)N_NODES * 4);
  int* row_ptr   = (int*)alloc((size_t)(N_NODES + 1) * 4);
  int* cursor    = (int*)alloc((size_t)N_NODES * 4);
  int* blockSums = (int*)alloc(512 * 4);
  int* csr_src   = (int*)alloc((size_t)N_EDGES * 4);
  unsigned short* xb   = (unsigned short*)alloc((size_t)N_NODES * K_DIM * 2);
  unsigned short* aggb = (unsigned short*)alloc((size_t)N_NODES * K_DIM * 2);
  unsigned short* h1   = (unsigned short*)alloc((size_t)N_NODES * K_DIM * 2);
  unsigned short* g    = (unsigned short*)alloc((size_t)N_NODES * M2 * 2);
  unsigned short* Ws1T = (unsigned short*)alloc((size_t)128 * 128 * 2);
  unsigned short* Wn1T = (unsigned short*)alloc((size_t)128 * 128 * 2);
  unsigned short* Ws2T = (unsigned short*)alloc((size_t)64 * 128 * 2);
  unsigned short* Wn2T = (unsigned short*)alloc((size_t)64 * 128 * 2);

  hipMemsetAsync(deg, 0, (size_t)N_NODES * 4, stream);

  // conversions
  {
    long n4 = (long)N_NODES * K_DIM / 4;
    conv_x_kernel<<<(int)((n4 + 255) / 256), 256, 0, stream>>>(x, xb, n4);
  }
  {
    dim3 grid(64, 4);
    conv_wt_kernel<<<grid, 256, 0, stream>>>(Ws1, Wn1, Ws2, Wn2, Ws1T, Wn1T, Ws2T, Wn2T);
  }

  // CSR build
  deg_count<<<(N_EDGES + 255) / 256, 256, 0, stream>>>(dst, deg, N_EDGES);
  scan1<<<SCAN_BLOCKS, 256, 0, stream>>>(deg, row_ptr, blockSums, N_NODES);
  scan2<<<1, 512, 0, stream>>>(blockSums, SCAN_BLOCKS);
  scan3<<<SCAN_BLOCKS, 256, 0, stream>>>(row_ptr, blockSums, cursor, N_NODES, N_EDGES);
  csr_fill<<<(N_EDGES + 255) / 256, 256, 0, stream>>>(src, dst, cursor, csr_src, N_EDGES);

  // layer 1
  {
    long t = (long)N_NODES * 16;
    aggregate128<<<(int)((t + 255) / 256), 256, 0, stream>>>(xb, row_ptr, csr_src, aggb, N_NODES);
  }
  gemm1_mfma<<<(N_NODES + 63) / 64, 256, 0, stream>>>(xb, aggb, Ws1T, Wn1T, b1, h1, N_NODES);

  // layer 2
  gemm2_mfma<<<(N_NODES + 63) / 64, 256, 0, stream>>>(h1, Ws2T, Wn2T, b2, out, g, N_NODES);
  {
    long t = (long)N_NODES * 8;
    aggregate64_add<<<(int)((t + 255) / 256), 256, 0, stream>>>(g, row_ptr, csr_src, out, N_NODES);
  }
}

// Round 4
// 310.419 us; speedup vs baseline: 7.7381x; 1.1038x over previous
//
#include <hip/hip_runtime.h>

#define N_NODES 100000
#define N_EDGES 600000
#define K_DIM 128
#define M2 64
#define SCAN_BLOCKS ((N_NODES + 255) / 256)   // 391

using frag_ab = __attribute__((ext_vector_type(8))) short;   // 8 bf16 = 4 VGPRs
using frag_cd = __attribute__((ext_vector_type(4))) float;   // 4 fp32 acc

// fp32 -> bf16 round-to-nearest-even
__device__ __forceinline__ unsigned short f2b(float f) {
  unsigned u = __builtin_bit_cast(unsigned, f);
  u = (u + 0x7fffu + ((u >> 16) & 1u)) >> 16;
  return (unsigned short)u;
}

// ---------------- convert x to bf16 ----------------
__global__ __launch_bounds__(256) void conv_x_kernel(const float* __restrict__ x,
                                                     unsigned short* __restrict__ xb,
                                                     long n4) {
  long i = (long)blockIdx.x * blockDim.x + threadIdx.x;
  if (i >= n4) return;
  float4 v = *(const float4*)(x + i * 4);
  ushort4 o;
  o.x = f2b(v.x); o.y = f2b(v.y); o.z = f2b(v.z); o.w = f2b(v.w);
  *(ushort4*)(xb + i * 4) = o;
}

// ---------------- convert + transpose weights: WT[n][k] = W[k][n], bf16 ----------------
__global__ __launch_bounds__(256) void conv_wt_kernel(const float* __restrict__ Ws1,
                                                      const float* __restrict__ Wn1,
                                                      const float* __restrict__ Ws2,
                                                      const float* __restrict__ Wn2,
                                                      unsigned short* __restrict__ Ws1T,
                                                      unsigned short* __restrict__ Wn1T,
                                                      unsigned short* __restrict__ Ws2T,
                                                      unsigned short* __restrict__ Wn2T) {
  int which = blockIdx.y;
  const float* W = (which == 0) ? Ws1 : (which == 1) ? Wn1 : (which == 2) ? Ws2 : Wn2;
  unsigned short* WT = (which == 0) ? Ws1T : (which == 1) ? Wn1T : (which == 2) ? Ws2T : Wn2T;
  int M = (which < 2) ? 128 : 64;
  int i = blockIdx.x * 256 + threadIdx.x;  // i = n*128 + k
  if (i >= M * 128) return;
  int n = i >> 7, k = i & 127;
  WT[i] = f2b(W[k * M + n]);
}

// ---------------- degree count ----------------
__global__ __launch_bounds__(256) void deg_count(const int* __restrict__ dst,
                                                 int* __restrict__ deg, int nE) {
  int i = blockIdx.x * blockDim.x + threadIdx.x;
  if (i < nE) atomicAdd(&deg[dst[i]], 1);
}

// ---------------- hierarchical exclusive scan ----------------
__global__ __launch_bounds__(256) void scan1(const int* __restrict__ deg,
                                             int* __restrict__ partial,
                                             int* __restrict__ blockSums, int n) {
  __shared__ int sdata[256];
  int tid = threadIdx.x;
  int i = blockIdx.x * 256 + tid;
  int v = (i < n) ? deg[i] : 0;
  sdata[tid] = v;
  __syncthreads();
#pragma unroll
  for (int off = 1; off < 256; off <<= 1) {
    int t = (tid >= off) ? sdata[tid - off] : 0;
    __syncthreads();
    sdata[tid] += t;
    __syncthreads();
  }
  if (i < n) partial[i] = sdata[tid] - v;
  if (tid == 255) blockSums[blockIdx.x] = sdata[255];
}

__global__ __launch_bounds__(512) void scan2(int* __restrict__ blockSums, int nb) {
  __shared__ int sdata[512];
  int tid = threadIdx.x;
  int v = (tid < nb) ? blockSums[tid] : 0;
  sdata[tid] = v;
  __syncthreads();
#pragma unroll
  for (int off = 1; off < 512; off <<= 1) {
    int t = (tid >= off) ? sdata[tid - off] : 0;
    __syncthreads();
    sdata[tid] += t;
    __syncthreads();
  }
  if (tid < nb) blockSums[tid] = sdata[tid] - v;
}

__global__ __launch_bounds__(256) void scan3(int* __restrict__ row_ptr,
                                             const int* __restrict__ blockSums,
                                             int* __restrict__ cursor, int n, int nE) {
  int i = blockIdx.x * 256 + threadIdx.x;
  if (i < n) {
    int val = row_ptr[i] + blockSums[i >> 8];
    row_ptr[i] = val;
    cursor[i] = val;
  }
  if (i == 0) row_ptr[n] = nE;
}

// ---------------- CSR fill ----------------
__global__ __launch_bounds__(256) void csr_fill(const int* __restrict__ src,
                                                const int* __restrict__ dst,
                                                int* __restrict__ cursor,
                                                int* __restrict__ csr_src, int nE) {
  int e = blockIdx.x * blockDim.x + threadIdx.x;
  if (e < nE) {
    int pos = atomicAdd(&cursor[dst[e]], 1);
    csr_src[pos] = src[e];
  }
}

// ---------------- gather-mean, 128 bf16 cols: 16 threads/node ----------------
__global__ __launch_bounds__(256) void aggregate128(const unsigned short* __restrict__ xb,
                                                    const int* __restrict__ row_ptr,
                                                    const int* __restrict__ csr_src,
                                                    unsigned short* __restrict__ agg, int n) {
  int t = blockIdx.x * blockDim.x + threadIdx.x;
  int node = t >> 4;
  int c = (t & 15) << 3;  // 8 bf16 per thread
  if (node >= n) return;
  int beg = row_ptr[node], end = row_ptr[node + 1];
  float acc[8];
#pragma unroll
  for (int j = 0; j < 8; ++j) acc[j] = 0.f;
  for (int e = beg; e < end; ++e) {
    int s = csr_src[e];
    uint4 v = *(const uint4*)(xb + (size_t)s * K_DIM + c);
    unsigned u[4] = {v.x, v.y, v.z, v.w};
#pragma unroll
    for (int j = 0; j < 4; ++j) {
      acc[2 * j]     += __builtin_bit_cast(float, u[j] << 16);
      acc[2 * j + 1] += __builtin_bit_cast(float, u[j] & 0xffff0000u);
    }
  }
  float inv = 1.0f / (float)max(end - beg, 1);
  uint4 o;
  unsigned* op = (unsigned*)&o;
#pragma unroll
  for (int j = 0; j < 4; ++j) {
    unsigned lo = f2b(acc[2 * j] * inv);
    unsigned hi = f2b(acc[2 * j + 1] * inv);
    op[j] = lo | (hi << 16);
  }
  *(uint4*)(agg + (size_t)node * K_DIM + c) = o;
}

// ---------------- gather-mean-add, 64 bf16 cols -> out fp32: 8 threads/node ----------------
__global__ __launch_bounds__(256) void aggregate64_add(const unsigned short* __restrict__ g,
                                                       const int* __restrict__ row_ptr,
                                                       const int* __restrict__ csr_src,
                                                       float* __restrict__ out, int n) {
  int t = blockIdx.x * blockDim.x + threadIdx.x;
  int node = t >> 3;
  int c = (t & 7) << 3;  // 8 bf16 per thread
  if (node >= n) return;
  int beg = row_ptr[node], end = row_ptr[node + 1];
  float acc[8];
#pragma unroll
  for (int j = 0; j < 8; ++j) acc[j] = 0.f;
  for (int e = beg; e < end; ++e) {
    int s = csr_src[e];
    uint4 v = *(const uint4*)(g + (size_t)s * M2 + c);
    unsigned u[4] = {v.x, v.y, v.z, v.w};
#pragma unroll
    for (int j = 0; j < 4; ++j) {
      acc[2 * j]     += __builtin_bit_cast(float, u[j] << 16);
      acc[2 * j + 1] += __builtin_bit_cast(float, u[j] & 0xffff0000u);
    }
  }
  float inv = 1.0f / (float)max(end - beg, 1);
  float* op = out + (size_t)node * M2 + c;
  float4 o0 = *(float4*)(op);
  float4 o1 = *(float4*)(op + 4);
  o0.x += acc[0] * inv; o0.y += acc[1] * inv; o0.z += acc[2] * inv; o0.w += acc[3] * inv;
  o1.x += acc[4] * inv; o1.y += acc[5] * inv; o1.z += acc[6] * inv; o1.w += acc[7] * inv;
  *(float4*)(op) = o0;
  *(float4*)(op + 4) = o1;
}

// ---------------- layer-1 MFMA GEMM v2: 128x128 block tile, wave = 64 rows x 64 cols ----------------
// h1 = relu(xb@Ws1 + aggb@Wn1 + b1), bf16 out.
// Per kb-step: 16 frag loads feed 32 MFMAs (4 row-tiles x 4 col-tiles x 2 matrices).
__global__ __launch_bounds__(256) void gemm1_mfma(const unsigned short* __restrict__ xb,
                                                  const unsigned short* __restrict__ aggb,
                                                  const unsigned short* __restrict__ WsT,
                                                  const unsigned short* __restrict__ WnT,
                                                  const float* __restrict__ bias,
                                                  unsigned short* __restrict__ h1, int N) {
  const int tid = threadIdx.x;
  const int wave = tid >> 6;
  const int lane = tid & 63;
  const int l15 = lane & 15;
  const int q = lane >> 4;
  const int rbase = blockIdx.x * 128 + (wave >> 1) * 64;
  const int ct0 = (wave & 1) * 4;  // col-tile offset (4 tiles = 64 cols per wave)

  const unsigned short* aptr[4];
  const unsigned short* gptr[4];
#pragma unroll
  for (int rt = 0; rt < 4; ++rt) {
    int m = rbase + rt * 16 + l15;
    int mc = (m < N) ? m : (N - 1);
    aptr[rt] = xb + (size_t)mc * K_DIM + q * 8;
    gptr[rt] = aggb + (size_t)mc * K_DIM + q * 8;
  }
  const unsigned short* wsb = WsT + (size_t)ct0 * (16 * K_DIM) + l15 * K_DIM + q * 8;
  const unsigned short* wnb = WnT + (size_t)ct0 * (16 * K_DIM) + l15 * K_DIM + q * 8;

  frag_cd acc[4][4];
#pragma unroll
  for (int rt = 0; rt < 4; ++rt)
#pragma unroll
    for (int ct = 0; ct < 4; ++ct) acc[rt][ct] = (frag_cd)(0.f);

#pragma unroll
  for (int kb = 0; kb < 4; ++kb) {
    frag_ab ax[4], ag[4];
#pragma unroll
    for (int rt = 0; rt < 4; ++rt) {
      ax[rt] = *(const frag_ab*)(aptr[rt] + kb * 32);
      ag[rt] = *(const frag_ab*)(gptr[rt] + kb * 32);
    }
#pragma unroll
    for (int ct = 0; ct < 4; ++ct) {
      frag_ab bs = *(const frag_ab*)(wsb + ct * (16 * K_DIM) + kb * 32);
      frag_ab bn = *(const frag_ab*)(wnb + ct * (16 * K_DIM) + kb * 32);
#pragma unroll
      for (int rt = 0; rt < 4; ++rt) {
        acc[rt][ct] = __builtin_amdgcn_mfma_f32_16x16x32_bf16(ax[rt], bs, acc[rt][ct], 0, 0, 0);
        acc[rt][ct] = __builtin_amdgcn_mfma_f32_16x16x32_bf16(ag[rt], bn, acc[rt][ct], 0, 0, 0);
      }
    }
  }

  // C/D layout: col = l15, row = q*4 + r (within each 16x16 tile)
#pragma unroll
  for (int ct = 0; ct < 4; ++ct) {
    int col = (ct0 + ct) * 16 + l15;
    float bv = bias[col];
#pragma unroll
    for (int rt = 0; rt < 4; ++rt) {
#pragma unroll
      for (int r = 0; r < 4; ++r) {
        int row = rbase + rt * 16 + q * 4 + r;
        if (row < N) {
          float v = fmaxf(acc[rt][ct][r] + bv, 0.f);
          h1[(size_t)row * K_DIM + col] = f2b(v);
        }
      }
    }
  }
}

// ---------------- layer-2 dual MFMA GEMM v2: wave = 64 rows x 32 cols of BOTH S and G ----------------
// s = h1@Ws2 + b2 -> out (fp32); g = h1@Wn2 -> bf16.
__global__ __launch_bounds__(256) void gemm2_mfma(const unsigned short* __restrict__ hb,
                                                  const unsigned short* __restrict__ WsT,
                                                  const unsigned short* __restrict__ WnT,
                                                  const float* __restrict__ bias,
                                                  float* __restrict__ sOut,
                                                  unsigned short* __restrict__ gOut, int N) {
  const int tid = threadIdx.x;
  const int wave = tid >> 6;
  const int lane = tid & 63;
  const int l15 = lane & 15;
  const int q = lane >> 4;
  const int rbase = blockIdx.x * 128 + (wave >> 1) * 64;
  const int ct0 = (wave & 1) * 2;  // 2 col-tiles = 32 cols per wave (of each output)

  const unsigned short* aptr[4];
#pragma unroll
  for (int rt = 0; rt < 4; ++rt) {
    int m = rbase + rt * 16 + l15;
    int mc = (m < N) ? m : (N - 1);
    aptr[rt] = hb + (size_t)mc * K_DIM + q * 8;
  }
  const unsigned short* wsb = WsT + (size_t)ct0 * (16 * K_DIM) + l15 * K_DIM + q * 8;
  const unsigned short* wnb = WnT + (size_t)ct0 * (16 * K_DIM) + l15 * K_DIM + q * 8;

  frag_cd accS[4][2], accG[4][2];
#pragma unroll
  for (int rt = 0; rt < 4; ++rt)
#pragma unroll
    for (int ct = 0; ct < 2; ++ct) { accS[rt][ct] = (frag_cd)(0.f); accG[rt][ct] = (frag_cd)(0.f); }

#pragma unroll
  for (int kb = 0; kb < 4; ++kb) {
    frag_ab ah[4];
#pragma unroll
    for (int rt = 0; rt < 4; ++rt) ah[rt] = *(const frag_ab*)(aptr[rt] + kb * 32);
#pragma unroll
    for (int ct = 0; ct < 2; ++ct) {
      frag_ab bs = *(const frag_ab*)(wsb + ct * (16 * K_DIM) + kb * 32);
      frag_ab bn = *(const frag_ab*)(wnb + ct * (16 * K_DIM) + kb * 32);
#pragma unroll
      for (int rt = 0; rt < 4; ++rt) {
        accS[rt][ct] = __builtin_amdgcn_mfma_f32_16x16x32_bf16(ah[rt], bs, accS[rt][ct], 0, 0, 0);
        accG[rt][ct] = __builtin_amdgcn_mfma_f32_16x16x32_bf16(ah[rt], bn, accG[rt][ct], 0, 0, 0);
      }
    }
  }

#pragma unroll
  for (int ct = 0; ct < 2; ++ct) {
    int col = (ct0 + ct) * 16 + l15;
    float bv = bias[col];
#pragma unroll
    for (int rt = 0; rt < 4; ++rt) {
#pragma unroll
      for (int r = 0; r < 4; ++r) {
        int row = rbase + rt * 16 + q * 4 + r;
        if (row < N) {
          sOut[(size_t)row * M2 + col] = accS[rt][ct][r] + bv;
          gOut[(size_t)row * M2 + col] = f2b(accG[rt][ct][r]);
        }
      }
    }
  }
}

extern "C" void kernel_launch(void* const* d_in, const int* in_sizes, int n_in,
                              void* d_out, int out_size, void* d_ws, size_t ws_size,
                              hipStream_t stream) {
  const float* x   = (const float*)d_in[0];
  const int*   src = (const int*)d_in[1];
  const int*   dst = (const int*)d_in[2];
  const float* Ws1 = (const float*)d_in[3];
  const float* Wn1 = (const float*)d_in[4];
  const float* b1  = (const float*)d_in[5];
  const float* Ws2 = (const float*)d_in[6];
  const float* Wn2 = (const float*)d_in[7];
  const float* b2  = (const float*)d_in[8];
  float* out = (float*)d_out;

  char* ws = (char*)d_ws;
  size_t off = 0;
  auto alloc = [&](size_t bytes) {
    void* p = ws + off;
    off = (off + bytes + 4095) & ~(size_t)4095;
    return p;
  };
  int* deg       = (int*)alloc((size_t)N_NODES * 4);
  int* row_ptr   = (int*)alloc((size_t)(N_NODES + 1) * 4);
  int* cursor    = (int*)alloc((size_t)N_NODES * 4);
  int* blockSums = (int*)alloc(512 * 4);
  int* csr_src   = (int*)alloc((size_t)N_EDGES * 4);
  unsigned short* xb   = (unsigned short*)alloc((size_t)N_NODES * K_DIM * 2);
  unsigned short* aggb = (unsigned short*)alloc((size_t)N_NODES * K_DIM * 2);
  unsigned short* h1   = (unsigned short*)alloc((size_t)N_NODES * K_DIM * 2);
  unsigned short* g    = (unsigned short*)alloc((size_t)N_NODES * M2 * 2);
  unsigned short* Ws1T = (unsigned short*)alloc((size_t)128 * 128 * 2);
  unsigned short* Wn1T = (unsigned short*)alloc((size_t)128 * 128 * 2);
  unsigned short* Ws2T = (unsigned short*)alloc((size_t)64 * 128 * 2);
  unsigned short* Wn2T = (unsigned short*)alloc((size_t)64 * 128 * 2);

  hipMemsetAsync(deg, 0, (size_t)N_NODES * 4, stream);

  // conversions
  {
    long n4 = (long)N_NODES * K_DIM / 4;
    conv_x_kernel<<<(int)((n4 + 255) / 256), 256, 0, stream>>>(x, xb, n4);
  }
  {
    dim3 grid(64, 4);
    conv_wt_kernel<<<grid, 256, 0, stream>>>(Ws1, Wn1, Ws2, Wn2, Ws1T, Wn1T, Ws2T, Wn2T);
  }

  // CSR build
  deg_count<<<(N_EDGES + 255) / 256, 256, 0, stream>>>(dst, deg, N_EDGES);
  scan1<<<SCAN_BLOCKS, 256, 0, stream>>>(deg, row_ptr, blockSums, N_NODES);
  scan2<<<1, 512, 0, stream>>>(blockSums, SCAN_BLOCKS);
  scan3<<<SCAN_BLOCKS, 256, 0, stream>>>(row_ptr, blockSums, cursor, N_NODES, N_EDGES);
  csr_fill<<<(N_EDGES + 255) / 256, 256, 0, stream>>>(src, dst, cursor, csr_src, N_EDGES);

  // layer 1
  {
    long t = (long)N_NODES * 16;
    aggregate128<<<(int)((t + 255) / 256), 256, 0, stream>>>(xb, row_ptr, csr_src, aggb, N_NODES);
  }
  gemm1_mfma<<<(N_NODES + 127) / 128, 256, 0, stream>>>(xb, aggb, Ws1T, Wn1T, b1, h1, N_NODES);

  // layer 2
  gemm2_mfma<<<(N_NODES + 127) / 128, 256, 0, stream>>>(h1, Ws2T, Wn2T, b2, out, g, N_NODES);
  {
    long t = (long)N_NODES * 8;
    aggregate64_add<<<(int)((t + 255) / 256), 256, 0, stream>>>(g, row_ptr, csr_src, out, N_NODES);
  }
}

// Round 5
// 278.219 us; speedup vs baseline: 8.6337x; 1.1157x over previous
//
#include <hip/hip_runtime.h>

#define N_NODES 100000
#define N_EDGES 600000
#define K_DIM 128
#define M2 64
#define SCAN_BLOCKS ((N_NODES + 255) / 256)   // 391

using frag_ab = __attribute__((ext_vector_type(8))) short;   // 8 bf16 = 4 VGPRs
using frag_cd = __attribute__((ext_vector_type(4))) float;   // 4 fp32 acc

// fp32 -> bf16 round-to-nearest-even
__device__ __forceinline__ unsigned short f2b(float f) {
  unsigned u = __builtin_bit_cast(unsigned, f);
  u = (u + 0x7fffu + ((u >> 16) & 1u)) >> 16;
  return (unsigned short)u;
}

// ---------------- convert x to bf16 ----------------
__global__ __launch_bounds__(256) void conv_x_kernel(const float* __restrict__ x,
                                                     unsigned short* __restrict__ xb,
                                                     long n4) {
  long i = (long)blockIdx.x * blockDim.x + threadIdx.x;
  if (i >= n4) return;
  float4 v = *(const float4*)(x + i * 4);
  ushort4 o;
  o.x = f2b(v.x); o.y = f2b(v.y); o.z = f2b(v.z); o.w = f2b(v.w);
  *(ushort4*)(xb + i * 4) = o;
}

// ---------------- convert + transpose weights: WT[n][k] = W[k][n], bf16 ----------------
__global__ __launch_bounds__(256) void conv_wt_kernel(const float* __restrict__ Ws1,
                                                      const float* __restrict__ Wn1,
                                                      const float* __restrict__ Ws2,
                                                      const float* __restrict__ Wn2,
                                                      unsigned short* __restrict__ Ws1T,
                                                      unsigned short* __restrict__ Wn1T,
                                                      unsigned short* __restrict__ Ws2T,
                                                      unsigned short* __restrict__ Wn2T) {
  int which = blockIdx.y;
  const float* W = (which == 0) ? Ws1 : (which == 1) ? Wn1 : (which == 2) ? Ws2 : Wn2;
  unsigned short* WT = (which == 0) ? Ws1T : (which == 1) ? Wn1T : (which == 2) ? Ws2T : Wn2T;
  int M = (which < 2) ? 128 : 64;
  int i = blockIdx.x * 256 + threadIdx.x;  // i = n*128 + k
  if (i >= M * 128) return;
  int n = i >> 7, k = i & 127;
  WT[i] = f2b(W[k * M + n]);
}

// ---------------- degree count ----------------
__global__ __launch_bounds__(256) void deg_count(const int* __restrict__ dst,
                                                 int* __restrict__ deg, int nE) {
  int i = blockIdx.x * blockDim.x + threadIdx.x;
  if (i < nE) atomicAdd(&deg[dst[i]], 1);
}

// ---------------- hierarchical exclusive scan ----------------
__global__ __launch_bounds__(256) void scan1(const int* __restrict__ deg,
                                             int* __restrict__ partial,
                                             int* __restrict__ blockSums, int n) {
  __shared__ int sdata[256];
  int tid = threadIdx.x;
  int i = blockIdx.x * 256 + tid;
  int v = (i < n) ? deg[i] : 0;
  sdata[tid] = v;
  __syncthreads();
#pragma unroll
  for (int off = 1; off < 256; off <<= 1) {
    int t = (tid >= off) ? sdata[tid - off] : 0;
    __syncthreads();
    sdata[tid] += t;
    __syncthreads();
  }
  if (i < n) partial[i] = sdata[tid] - v;
  if (tid == 255) blockSums[blockIdx.x] = sdata[255];
}

__global__ __launch_bounds__(512) void scan2(int* __restrict__ blockSums, int nb) {
  __shared__ int sdata[512];
  int tid = threadIdx.x;
  int v = (tid < nb) ? blockSums[tid] : 0;
  sdata[tid] = v;
  __syncthreads();
#pragma unroll
  for (int off = 1; off < 512; off <<= 1) {
    int t = (tid >= off) ? sdata[tid - off] : 0;
    __syncthreads();
    sdata[tid] += t;
    __syncthreads();
  }
  if (tid < nb) blockSums[tid] = sdata[tid] - v;
}

__global__ __launch_bounds__(256) void scan3(int* __restrict__ row_ptr,
                                             const int* __restrict__ blockSums,
                                             int* __restrict__ cursor, int n, int nE) {
  int i = blockIdx.x * 256 + threadIdx.x;
  if (i < n) {
    int val = row_ptr[i] + blockSums[i >> 8];
    row_ptr[i] = val;
    cursor[i] = val;
  }
  if (i == 0) row_ptr[n] = nE;
}

// ---------------- CSR fill ----------------
__global__ __launch_bounds__(256) void csr_fill(const int* __restrict__ src,
                                                const int* __restrict__ dst,
                                                int* __restrict__ cursor,
                                                int* __restrict__ csr_src, int nE) {
  int e = blockIdx.x * blockDim.x + threadIdx.x;
  if (e < nE) {
    int pos = atomicAdd(&cursor[dst[e]], 1);
    csr_src[pos] = src[e];
  }
}

// ---------------- gather-mean, 128 bf16 cols: 16 threads/node ----------------
__global__ __launch_bounds__(256) void aggregate128(const unsigned short* __restrict__ xb,
                                                    const int* __restrict__ row_ptr,
                                                    const int* __restrict__ csr_src,
                                                    unsigned short* __restrict__ agg, int n) {
  int t = blockIdx.x * blockDim.x + threadIdx.x;
  int node = t >> 4;
  int c = (t & 15) << 3;  // 8 bf16 per thread
  if (node >= n) return;
  int beg = row_ptr[node], end = row_ptr[node + 1];
  float acc[8];
#pragma unroll
  for (int j = 0; j < 8; ++j) acc[j] = 0.f;
  for (int e = beg; e < end; ++e) {
    int s = csr_src[e];
    uint4 v = *(const uint4*)(xb + (size_t)s * K_DIM + c);
    unsigned u[4] = {v.x, v.y, v.z, v.w};
#pragma unroll
    for (int j = 0; j < 4; ++j) {
      acc[2 * j]     += __builtin_bit_cast(float, u[j] << 16);
      acc[2 * j + 1] += __builtin_bit_cast(float, u[j] & 0xffff0000u);
    }
  }
  float inv = 1.0f / (float)max(end - beg, 1);
  uint4 o;
  unsigned* op = (unsigned*)&o;
#pragma unroll
  for (int j = 0; j < 4; ++j) {
    unsigned lo = f2b(acc[2 * j] * inv);
    unsigned hi = f2b(acc[2 * j + 1] * inv);
    op[j] = lo | (hi << 16);
  }
  *(uint4*)(agg + (size_t)node * K_DIM + c) = o;
}

// ---------------- gather-mean-add, 64 bf16 cols -> out fp32: 8 threads/node ----------------
__global__ __launch_bounds__(256) void aggregate64_add(const unsigned short* __restrict__ g,
                                                       const int* __restrict__ row_ptr,
                                                       const int* __restrict__ csr_src,
                                                       float* __restrict__ out, int n) {
  int t = blockIdx.x * blockDim.x + threadIdx.x;
  int node = t >> 3;
  int c = (t & 7) << 3;  // 8 bf16 per thread
  if (node >= n) return;
  int beg = row_ptr[node], end = row_ptr[node + 1];
  float acc[8];
#pragma unroll
  for (int j = 0; j < 8; ++j) acc[j] = 0.f;
  for (int e = beg; e < end; ++e) {
    int s = csr_src[e];
    uint4 v = *(const uint4*)(g + (size_t)s * M2 + c);
    unsigned u[4] = {v.x, v.y, v.z, v.w};
#pragma unroll
    for (int j = 0; j < 4; ++j) {
      acc[2 * j]     += __builtin_bit_cast(float, u[j] << 16);
      acc[2 * j + 1] += __builtin_bit_cast(float, u[j] & 0xffff0000u);
    }
  }
  float inv = 1.0f / (float)max(end - beg, 1);
  float* op = out + (size_t)node * M2 + c;
  float4 o0 = *(float4*)(op);
  float4 o1 = *(float4*)(op + 4);
  o0.x += acc[0] * inv; o0.y += acc[1] * inv; o0.z += acc[2] * inv; o0.w += acc[3] * inv;
  o1.x += acc[4] * inv; o1.y += acc[5] * inv; o1.z += acc[6] * inv; o1.w += acc[7] * inv;
  *(float4*)(op) = o0;
  *(float4*)(op + 4) = o1;
}

// ---------------- fused both-layer GEMM ----------------
// Phase 1: h1 = relu(xb@Ws1 + aggb@Wn1 + b1)  -> LDS tile (128 nodes x 128 feat)
// Phase 2: out = h1@Ws2 + b2 (fp32), g = h1@Wn2 (bf16)
// Transposed MFMA: A = weight tile (feat = lane&15), B = node rows (node = lane&15);
// D[feat][node]: node = lane&15, feat = q*4+r -> lane holds 4 CONSECUTIVE features
// of one node => vectorized stores.
// Block = 4 waves = 128 nodes; wave: nodehalf = w>>1, feathalf/outmat = w&1.
#define LD1 132   // LDS row stride in bf16 elems (264 B: 8B-aligned rows, bank stride 2 -> 2-way max)
__global__ __launch_bounds__(256) void sage_fused_gemm(const unsigned short* __restrict__ xb,
                                                       const unsigned short* __restrict__ aggb,
                                                       const unsigned short* __restrict__ Ws1T,
                                                       const unsigned short* __restrict__ Wn1T,
                                                       const float* __restrict__ b1,
                                                       const unsigned short* __restrict__ Ws2T,
                                                       const unsigned short* __restrict__ Wn2T,
                                                       const float* __restrict__ b2,
                                                       float* __restrict__ out,
                                                       unsigned short* __restrict__ g, int N) {
  __shared__ unsigned short h1s[128 * LD1];

  const int tid = threadIdx.x;
  const int wave = tid >> 6;
  const int lane = tid & 63;
  const int l15 = lane & 15;
  const int q = lane >> 4;
  const int nodehalf = wave >> 1;
  const int fhalf = wave & 1;
  const int nbase_l = nodehalf * 64;
  const int nbase_g = blockIdx.x * 128 + nbase_l;
  const int fbase = fhalf * 64;

  // ---- phase 1: prefetch all x/agg fragments (32 outstanding 16-B loads) ----
  frag_ab ax[4][4], ag[4][4];
#pragma unroll
  for (int nt = 0; nt < 4; ++nt) {
    int m = nbase_g + nt * 16 + l15;
    int mc = (m < N) ? m : (N - 1);
    const unsigned short* xr = xb + (size_t)mc * K_DIM + q * 8;
    const unsigned short* gr = aggb + (size_t)mc * K_DIM + q * 8;
#pragma unroll
    for (int kb = 0; kb < 4; ++kb) {
      ax[nt][kb] = *(const frag_ab*)(xr + kb * 32);
      ag[nt][kb] = *(const frag_ab*)(gr + kb * 32);
    }
  }

  frag_cd acc[4][4];  // [nt][ft]
#pragma unroll
  for (int nt = 0; nt < 4; ++nt)
#pragma unroll
    for (int ft = 0; ft < 4; ++ft) acc[nt][ft] = (frag_cd)(0.f);

  const unsigned short* wsp = Ws1T + (size_t)(fbase + l15) * K_DIM + q * 8;
  const unsigned short* wnp = Wn1T + (size_t)(fbase + l15) * K_DIM + q * 8;
#pragma unroll
  for (int kb = 0; kb < 4; ++kb) {
#pragma unroll
    for (int ft = 0; ft < 4; ++ft) {
      frag_ab fs = *(const frag_ab*)(wsp + ft * (16 * K_DIM) + kb * 32);
      frag_ab fn = *(const frag_ab*)(wnp + ft * (16 * K_DIM) + kb * 32);
#pragma unroll
      for (int nt = 0; nt < 4; ++nt) {
        acc[nt][ft] = __builtin_amdgcn_mfma_f32_16x16x32_bf16(fs, ax[nt][kb], acc[nt][ft], 0, 0, 0);
        acc[nt][ft] = __builtin_amdgcn_mfma_f32_16x16x32_bf16(fn, ag[nt][kb], acc[nt][ft], 0, 0, 0);
      }
    }
  }

  // epilogue 1: relu(acc + b1) -> LDS, 8-B stores (4 consecutive feats per lane)
#pragma unroll
  for (int ft = 0; ft < 4; ++ft) {
    int f0 = fbase + ft * 16 + q * 4;
    float4 bv = *(const float4*)(b1 + f0);
#pragma unroll
    for (int nt = 0; nt < 4; ++nt) {
      int nl = nbase_l + nt * 16 + l15;
      ushort4 o;
      o.x = f2b(fmaxf(acc[nt][ft][0] + bv.x, 0.f));
      o.y = f2b(fmaxf(acc[nt][ft][1] + bv.y, 0.f));
      o.z = f2b(fmaxf(acc[nt][ft][2] + bv.z, 0.f));
      o.w = f2b(fmaxf(acc[nt][ft][3] + bv.w, 0.f));
      *(ushort4*)(h1s + nl * LD1 + f0) = o;
    }
  }
  __syncthreads();

  // ---- phase 2: prefetch h1 fragments from LDS ----
  frag_ab ah[4][4];
#pragma unroll
  for (int nt = 0; nt < 4; ++nt) {
    const unsigned short* hr = h1s + (nbase_l + nt * 16 + l15) * LD1 + q * 8;
#pragma unroll
    for (int kb = 0; kb < 4; ++kb) ah[nt][kb] = *(const frag_ab*)(hr + kb * 32);
  }

  const unsigned short* W2 = fhalf ? Wn2T : Ws2T;  // wave's output matrix
  const unsigned short* wp = W2 + (size_t)l15 * K_DIM + q * 8;
  frag_cd acc2[4][4];
#pragma unroll
  for (int nt = 0; nt < 4; ++nt)
#pragma unroll
    for (int ft = 0; ft < 4; ++ft) acc2[nt][ft] = (frag_cd)(0.f);

#pragma unroll
  for (int kb = 0; kb < 4; ++kb) {
#pragma unroll
    for (int ft = 0; ft < 4; ++ft) {
      frag_ab wf = *(const frag_ab*)(wp + ft * (16 * K_DIM) + kb * 32);
#pragma unroll
      for (int nt = 0; nt < 4; ++nt)
        acc2[nt][ft] = __builtin_amdgcn_mfma_f32_16x16x32_bf16(wf, ah[nt][kb], acc2[nt][ft], 0, 0, 0);
    }
  }

  // epilogue 2: fhalf==0 -> out fp32 (+b2), fhalf==1 -> g bf16
  if (fhalf == 0) {
#pragma unroll
    for (int ft = 0; ft < 4; ++ft) {
      int f0 = ft * 16 + q * 4;
      float4 bv = *(const float4*)(b2 + f0);
#pragma unroll
      for (int nt = 0; nt < 4; ++nt) {
        int node = nbase_g + nt * 16 + l15;
        if (node < N) {
          float4 o;
          o.x = acc2[nt][ft][0] + bv.x;
          o.y = acc2[nt][ft][1] + bv.y;
          o.z = acc2[nt][ft][2] + bv.z;
          o.w = acc2[nt][ft][3] + bv.w;
          *(float4*)(out + (size_t)node * M2 + f0) = o;
        }
      }
    }
  } else {
#pragma unroll
    for (int ft = 0; ft < 4; ++ft) {
      int f0 = ft * 16 + q * 4;
#pragma unroll
      for (int nt = 0; nt < 4; ++nt) {
        int node = nbase_g + nt * 16 + l15;
        if (node < N) {
          ushort4 o;
          o.x = f2b(acc2[nt][ft][0]);
          o.y = f2b(acc2[nt][ft][1]);
          o.z = f2b(acc2[nt][ft][2]);
          o.w = f2b(acc2[nt][ft][3]);
          *(ushort4*)(g + (size_t)node * M2 + f0) = o;
        }
      }
    }
  }
}

extern "C" void kernel_launch(void* const* d_in, const int* in_sizes, int n_in,
                              void* d_out, int out_size, void* d_ws, size_t ws_size,
                              hipStream_t stream) {
  const float* x   = (const float*)d_in[0];
  const int*   src = (const int*)d_in[1];
  const int*   dst = (const int*)d_in[2];
  const float* Ws1 = (const float*)d_in[3];
  const float* Wn1 = (const float*)d_in[4];
  const float* b1  = (const float*)d_in[5];
  const float* Ws2 = (const float*)d_in[6];
  const float* Wn2 = (const float*)d_in[7];
  const float* b2  = (const float*)d_in[8];
  float* out = (float*)d_out;

  char* ws = (char*)d_ws;
  size_t off = 0;
  auto alloc = [&](size_t bytes) {
    void* p = ws + off;
    off = (off + bytes + 4095) & ~(size_t)4095;
    return p;
  };
  int* deg       = (int*)alloc((size_t)N_NODES * 4);
  int* row_ptr   = (int*)alloc((size_t)(N_NODES + 1) * 4);
  int* cursor    = (int*)alloc((size_t)N_NODES * 4);
  int* blockSums = (int*)alloc(512 * 4);
  int* csr_src   = (int*)alloc((size_t)N_EDGES * 4);
  unsigned short* xb   = (unsigned short*)alloc((size_t)N_NODES * K_DIM * 2);
  unsigned short* aggb = (unsigned short*)alloc((size_t)N_NODES * K_DIM * 2);
  unsigned short* g    = (unsigned short*)alloc((size_t)N_NODES * M2 * 2);
  unsigned short* Ws1T = (unsigned short*)alloc((size_t)128 * 128 * 2);
  unsigned short* Wn1T = (unsigned short*)alloc((size_t)128 * 128 * 2);
  unsigned short* Ws2T = (unsigned short*)alloc((size_t)64 * 128 * 2);
  unsigned short* Wn2T = (unsigned short*)alloc((size_t)64 * 128 * 2);

  hipMemsetAsync(deg, 0, (size_t)N_NODES * 4, stream);

  // conversions
  {
    long n4 = (long)N_NODES * K_DIM / 4;
    conv_x_kernel<<<(int)((n4 + 255) / 256), 256, 0, stream>>>(x, xb, n4);
  }
  {
    dim3 grid(64, 4);
    conv_wt_kernel<<<grid, 256, 0, stream>>>(Ws1, Wn1, Ws2, Wn2, Ws1T, Wn1T, Ws2T, Wn2T);
  }

  // CSR build
  deg_count<<<(N_EDGES + 255) / 256, 256, 0, stream>>>(dst, deg, N_EDGES);
  scan1<<<SCAN_BLOCKS, 256, 0, stream>>>(deg, row_ptr, blockSums, N_NODES);
  scan2<<<1, 512, 0, stream>>>(blockSums, SCAN_BLOCKS);
  scan3<<<SCAN_BLOCKS, 256, 0, stream>>>(row_ptr, blockSums, cursor, N_NODES, N_EDGES);
  csr_fill<<<(N_EDGES + 255) / 256, 256, 0, stream>>>(src, dst, cursor, csr_src, N_EDGES);

  // layer-1 aggregation
  {
    long t = (long)N_NODES * 16;
    aggregate128<<<(int)((t + 255) / 256), 256, 0, stream>>>(xb, row_ptr, csr_src, aggb, N_NODES);
  }

  // fused layer-1 + layer-2 GEMMs (h1 stays in LDS)
  sage_fused_gemm<<<(N_NODES + 127) / 128, 256, 0, stream>>>(
      xb, aggb, Ws1T, Wn1T, b1, Ws2T, Wn2T, b2, out, g, N_NODES);

  // layer-2 aggregation (adds mean(g) into out)
  {
    long t = (long)N_NODES * 8;
    aggregate64_add<<<(int)((t + 255) / 256), 256, 0, stream>>>(g, row_ptr, csr_src, out, N_NODES);
  }
}

// Round 6
// 277.509 us; speedup vs baseline: 8.6558x; 1.0026x over previous
//
#include <hip/hip_runtime.h>

#define N_NODES 100000
#define N_EDGES 600000
#define K_DIM 128
#define M2 64
#define SCAN_BLOCKS ((N_NODES + 255) / 256)   // 391

using frag_ab = __attribute__((ext_vector_type(8))) short;   // 8 bf16 = 4 VGPRs
using frag_cd = __attribute__((ext_vector_type(4))) float;   // 4 fp32 acc

// fp32 -> bf16 round-to-nearest-even
__device__ __forceinline__ unsigned short f2b(float f) {
  unsigned u = __builtin_bit_cast(unsigned, f);
  u = (u + 0x7fffu + ((u >> 16) & 1u)) >> 16;
  return (unsigned short)u;
}

// ---------------- convert x to bf16 ----------------
__global__ __launch_bounds__(256) void conv_x_kernel(const float* __restrict__ x,
                                                     unsigned short* __restrict__ xb,
                                                     long n4) {
  long i = (long)blockIdx.x * blockDim.x + threadIdx.x;
  if (i >= n4) return;
  float4 v = *(const float4*)(x + i * 4);
  ushort4 o;
  o.x = f2b(v.x); o.y = f2b(v.y); o.z = f2b(v.z); o.w = f2b(v.w);
  *(ushort4*)(xb + i * 4) = o;
}

// ---------------- convert + transpose weights: WT[n][k] = W[k][n], bf16 ----------------
__global__ __launch_bounds__(256) void conv_wt_kernel(const float* __restrict__ Ws1,
                                                      const float* __restrict__ Wn1,
                                                      const float* __restrict__ Ws2,
                                                      const float* __restrict__ Wn2,
                                                      unsigned short* __restrict__ Ws1T,
                                                      unsigned short* __restrict__ Wn1T,
                                                      unsigned short* __restrict__ Ws2T,
                                                      unsigned short* __restrict__ Wn2T) {
  int which = blockIdx.y;
  const float* W = (which == 0) ? Ws1 : (which == 1) ? Wn1 : (which == 2) ? Ws2 : Wn2;
  unsigned short* WT = (which == 0) ? Ws1T : (which == 1) ? Wn1T : (which == 2) ? Ws2T : Wn2T;
  int M = (which < 2) ? 128 : 64;
  int i = blockIdx.x * 256 + threadIdx.x;  // i = n*128 + k
  if (i >= M * 128) return;
  int n = i >> 7, k = i & 127;
  WT[i] = f2b(W[k * M + n]);
}

// ---------------- degree count ----------------
__global__ __launch_bounds__(256) void deg_count(const int* __restrict__ dst,
                                                 int* __restrict__ deg, int nE) {
  int i = blockIdx.x * blockDim.x + threadIdx.x;
  if (i < nE) atomicAdd(&deg[dst[i]], 1);
}

// ---------------- hierarchical exclusive scan ----------------
__global__ __launch_bounds__(256) void scan1(const int* __restrict__ deg,
                                             int* __restrict__ partial,
                                             int* __restrict__ blockSums, int n) {
  __shared__ int sdata[256];
  int tid = threadIdx.x;
  int i = blockIdx.x * 256 + tid;
  int v = (i < n) ? deg[i] : 0;
  sdata[tid] = v;
  __syncthreads();
#pragma unroll
  for (int off = 1; off < 256; off <<= 1) {
    int t = (tid >= off) ? sdata[tid - off] : 0;
    __syncthreads();
    sdata[tid] += t;
    __syncthreads();
  }
  if (i < n) partial[i] = sdata[tid] - v;
  if (tid == 255) blockSums[blockIdx.x] = sdata[255];
}

__global__ __launch_bounds__(512) void scan2(int* __restrict__ blockSums, int nb) {
  __shared__ int sdata[512];
  int tid = threadIdx.x;
  int v = (tid < nb) ? blockSums[tid] : 0;
  sdata[tid] = v;
  __syncthreads();
#pragma unroll
  for (int off = 1; off < 512; off <<= 1) {
    int t = (tid >= off) ? sdata[tid - off] : 0;
    __syncthreads();
    sdata[tid] += t;
    __syncthreads();
  }
  if (tid < nb) blockSums[tid] = sdata[tid] - v;
}

__global__ __launch_bounds__(256) void scan3(int* __restrict__ row_ptr,
                                             const int* __restrict__ blockSums,
                                             int* __restrict__ cursor, int n, int nE) {
  int i = blockIdx.x * 256 + threadIdx.x;
  if (i < n) {
    int val = row_ptr[i] + blockSums[i >> 8];
    row_ptr[i] = val;
    cursor[i] = val;
  }
  if (i == 0) row_ptr[n] = nE;
}

// ---------------- CSR fill ----------------
__global__ __launch_bounds__(256) void csr_fill(const int* __restrict__ src,
                                                const int* __restrict__ dst,
                                                int* __restrict__ cursor,
                                                int* __restrict__ csr_src, int nE) {
  int e = blockIdx.x * blockDim.x + threadIdx.x;
  if (e < nE) {
    int pos = atomicAdd(&cursor[dst[e]], 1);
    csr_src[pos] = src[e];
  }
}

// ---------------- gather-mean, 128 bf16 cols: 16 threads/node, 4-way pipelined ----------------
__global__ __launch_bounds__(256) void aggregate128(const unsigned short* __restrict__ xb,
                                                    const int* __restrict__ row_ptr,
                                                    const int* __restrict__ csr_src,
                                                    unsigned short* __restrict__ agg, int n) {
  int t = blockIdx.x * blockDim.x + threadIdx.x;
  int node = t >> 4;
  int c = (t & 15) << 3;  // 8 bf16 per thread
  if (node >= n) return;
  int beg = row_ptr[node], end = row_ptr[node + 1];
  float acc[8];
#pragma unroll
  for (int j = 0; j < 8; ++j) acc[j] = 0.f;

  int e = beg;
  for (; e + 4 <= end; e += 4) {
    int s0 = csr_src[e], s1 = csr_src[e + 1], s2 = csr_src[e + 2], s3 = csr_src[e + 3];
    uint4 v0 = *(const uint4*)(xb + (size_t)s0 * K_DIM + c);
    uint4 v1 = *(const uint4*)(xb + (size_t)s1 * K_DIM + c);
    uint4 v2 = *(const uint4*)(xb + (size_t)s2 * K_DIM + c);
    uint4 v3 = *(const uint4*)(xb + (size_t)s3 * K_DIM + c);
    unsigned u[4][4] = {{v0.x, v0.y, v0.z, v0.w}, {v1.x, v1.y, v1.z, v1.w},
                        {v2.x, v2.y, v2.z, v2.w}, {v3.x, v3.y, v3.z, v3.w}};
#pragma unroll
    for (int p = 0; p < 4; ++p)
#pragma unroll
      for (int j = 0; j < 4; ++j) {
        acc[2 * j]     += __builtin_bit_cast(float, u[p][j] << 16);
        acc[2 * j + 1] += __builtin_bit_cast(float, u[p][j] & 0xffff0000u);
      }
  }
  for (; e < end; ++e) {
    int s = csr_src[e];
    uint4 v = *(const uint4*)(xb + (size_t)s * K_DIM + c);
    unsigned u[4] = {v.x, v.y, v.z, v.w};
#pragma unroll
    for (int j = 0; j < 4; ++j) {
      acc[2 * j]     += __builtin_bit_cast(float, u[j] << 16);
      acc[2 * j + 1] += __builtin_bit_cast(float, u[j] & 0xffff0000u);
    }
  }
  float inv = 1.0f / (float)max(end - beg, 1);
  uint4 o;
  unsigned* op = (unsigned*)&o;
#pragma unroll
  for (int j = 0; j < 4; ++j) {
    unsigned lo = f2b(acc[2 * j] * inv);
    unsigned hi = f2b(acc[2 * j + 1] * inv);
    op[j] = lo | (hi << 16);
  }
  *(uint4*)(agg + (size_t)node * K_DIM + c) = o;
}

// ---------------- gather-mean-add, 64 bf16 cols -> out fp32: 8 threads/node, 4-way pipelined ----------------
__global__ __launch_bounds__(256) void aggregate64_add(const unsigned short* __restrict__ g,
                                                       const int* __restrict__ row_ptr,
                                                       const int* __restrict__ csr_src,
                                                       float* __restrict__ out, int n) {
  int t = blockIdx.x * blockDim.x + threadIdx.x;
  int node = t >> 3;
  int c = (t & 7) << 3;  // 8 bf16 per thread
  if (node >= n) return;
  int beg = row_ptr[node], end = row_ptr[node + 1];
  float acc[8];
#pragma unroll
  for (int j = 0; j < 8; ++j) acc[j] = 0.f;

  int e = beg;
  for (; e + 4 <= end; e += 4) {
    int s0 = csr_src[e], s1 = csr_src[e + 1], s2 = csr_src[e + 2], s3 = csr_src[e + 3];
    uint4 v0 = *(const uint4*)(g + (size_t)s0 * M2 + c);
    uint4 v1 = *(const uint4*)(g + (size_t)s1 * M2 + c);
    uint4 v2 = *(const uint4*)(g + (size_t)s2 * M2 + c);
    uint4 v3 = *(const uint4*)(g + (size_t)s3 * M2 + c);
    unsigned u[4][4] = {{v0.x, v0.y, v0.z, v0.w}, {v1.x, v1.y, v1.z, v1.w},
                        {v2.x, v2.y, v2.z, v2.w}, {v3.x, v3.y, v3.z, v3.w}};
#pragma unroll
    for (int p = 0; p < 4; ++p)
#pragma unroll
      for (int j = 0; j < 4; ++j) {
        acc[2 * j]     += __builtin_bit_cast(float, u[p][j] << 16);
        acc[2 * j + 1] += __builtin_bit_cast(float, u[p][j] & 0xffff0000u);
      }
  }
  for (; e < end; ++e) {
    int s = csr_src[e];
    uint4 v = *(const uint4*)(g + (size_t)s * M2 + c);
    unsigned u[4] = {v.x, v.y, v.z, v.w};
#pragma unroll
    for (int j = 0; j < 4; ++j) {
      acc[2 * j]     += __builtin_bit_cast(float, u[j] << 16);
      acc[2 * j + 1] += __builtin_bit_cast(float, u[j] & 0xffff0000u);
    }
  }
  float inv = 1.0f / (float)max(end - beg, 1);
  float* op = out + (size_t)node * M2 + c;
  float4 o0 = *(float4*)(op);
  float4 o1 = *(float4*)(op + 4);
  o0.x += acc[0] * inv; o0.y += acc[1] * inv; o0.z += acc[2] * inv; o0.w += acc[3] * inv;
  o1.x += acc[4] * inv; o1.y += acc[5] * inv; o1.z += acc[6] * inv; o1.w += acc[7] * inv;
  *(float4*)(op) = o0;
  *(float4*)(op + 4) = o1;
}

// ---------------- fused both-layer GEMM, 64-node blocks ----------------
// Phase 1: h1 = relu(xb@Ws1 + aggb@Wn1 + b1) -> LDS (64 nodes x 128 feat)
// Phase 2: out = h1@Ws2 + b2 (fp32), g = h1@Wn2 (bf16)
// Operand-swapped MFMA: A = weight rows (feat=lane&15), B = node rows (node=lane&15);
// D: node = lane&15, feat = q*4+r -> vectorized stores.
// 4 waves: nh = wave>>1 -> nodes nh*32..+31; fhalf = wave&1 -> feat half (p1) / S-vs-G (p2).
#define LD1 132   // LDS row stride (264 B): 16 rows spread over even banks, 2-way max (free)
__global__ __launch_bounds__(256) void sage_fused_gemm(const unsigned short* __restrict__ xb,
                                                       const unsigned short* __restrict__ aggb,
                                                       const unsigned short* __restrict__ Ws1T,
                                                       const unsigned short* __restrict__ Wn1T,
                                                       const float* __restrict__ b1,
                                                       const unsigned short* __restrict__ Ws2T,
                                                       const unsigned short* __restrict__ Wn2T,
                                                       const float* __restrict__ b2,
                                                       float* __restrict__ out,
                                                       unsigned short* __restrict__ g, int N) {
  __shared__ unsigned short h1s[64 * LD1];  // 16.9 KB

  const int tid = threadIdx.x;
  const int wave = tid >> 6;
  const int lane = tid & 63;
  const int l15 = lane & 15;
  const int q = lane >> 4;
  const int nh = wave >> 1;
  const int fhalf = wave & 1;
  const int nbase_l = nh * 32;
  const int nbase_g = blockIdx.x * 64 + nbase_l;
  const int fbase = fhalf * 64;

  // ---- phase 1: prefetch x/agg fragments (16 outstanding 16-B loads) ----
  frag_ab ax[2][4], ag[2][4];
#pragma unroll
  for (int nt = 0; nt < 2; ++nt) {
    int m = nbase_g + nt * 16 + l15;
    int mc = (m < N) ? m : (N - 1);
    const unsigned short* xr = xb + (size_t)mc * K_DIM + q * 8;
    const unsigned short* gr = aggb + (size_t)mc * K_DIM + q * 8;
#pragma unroll
    for (int kb = 0; kb < 4; ++kb) {
      ax[nt][kb] = *(const frag_ab*)(xr + kb * 32);
      ag[nt][kb] = *(const frag_ab*)(gr + kb * 32);
    }
  }

  frag_cd acc[2][4];  // [nt][ft]
#pragma unroll
  for (int nt = 0; nt < 2; ++nt)
#pragma unroll
    for (int ft = 0; ft < 4; ++ft) acc[nt][ft] = (frag_cd)(0.f);

  const unsigned short* wsp = Ws1T + (size_t)(fbase + l15) * K_DIM + q * 8;
  const unsigned short* wnp = Wn1T + (size_t)(fbase + l15) * K_DIM + q * 8;
#pragma unroll
  for (int kb = 0; kb < 4; ++kb) {
#pragma unroll
    for (int ft = 0; ft < 4; ++ft) {
      frag_ab fs = *(const frag_ab*)(wsp + ft * (16 * K_DIM) + kb * 32);
      frag_ab fn = *(const frag_ab*)(wnp + ft * (16 * K_DIM) + kb * 32);
#pragma unroll
      for (int nt = 0; nt < 2; ++nt) {
        acc[nt][ft] = __builtin_amdgcn_mfma_f32_16x16x32_bf16(fs, ax[nt][kb], acc[nt][ft], 0, 0, 0);
        acc[nt][ft] = __builtin_amdgcn_mfma_f32_16x16x32_bf16(fn, ag[nt][kb], acc[nt][ft], 0, 0, 0);
      }
    }
  }

  // epilogue 1: relu(acc + b1) -> LDS, 8-B stores
#pragma unroll
  for (int ft = 0; ft < 4; ++ft) {
    int f0 = fbase + ft * 16 + q * 4;
    float4 bv = *(const float4*)(b1 + f0);
#pragma unroll
    for (int nt = 0; nt < 2; ++nt) {
      int nl = nbase_l + nt * 16 + l15;
      ushort4 o;
      o.x = f2b(fmaxf(acc[nt][ft][0] + bv.x, 0.f));
      o.y = f2b(fmaxf(acc[nt][ft][1] + bv.y, 0.f));
      o.z = f2b(fmaxf(acc[nt][ft][2] + bv.z, 0.f));
      o.w = f2b(fmaxf(acc[nt][ft][3] + bv.w, 0.f));
      *(ushort4*)(h1s + nl * LD1 + f0) = o;
    }
  }
  __syncthreads();

  // ---- phase 2: h1 fragments from LDS ----
  frag_ab ah[2][4];
#pragma unroll
  for (int nt = 0; nt < 2; ++nt) {
    const unsigned short* hr = h1s + (nbase_l + nt * 16 + l15) * LD1 + q * 8;
#pragma unroll
    for (int kb = 0; kb < 4; ++kb) ah[nt][kb] = *(const frag_ab*)(hr + kb * 32);
  }

  const unsigned short* W2 = fhalf ? Wn2T : Ws2T;
  const unsigned short* wp = W2 + (size_t)l15 * K_DIM + q * 8;
  frag_cd acc2[2][4];
#pragma unroll
  for (int nt = 0; nt < 2; ++nt)
#pragma unroll
    for (int ft = 0; ft < 4; ++ft) acc2[nt][ft] = (frag_cd)(0.f);

#pragma unroll
  for (int kb = 0; kb < 4; ++kb) {
#pragma unroll
    for (int ft = 0; ft < 4; ++ft) {
      frag_ab wf = *(const frag_ab*)(wp + ft * (16 * K_DIM) + kb * 32);
#pragma unroll
      for (int nt = 0; nt < 2; ++nt)
        acc2[nt][ft] = __builtin_amdgcn_mfma_f32_16x16x32_bf16(wf, ah[nt][kb], acc2[nt][ft], 0, 0, 0);
    }
  }

  // epilogue 2: fhalf==0 -> out fp32 (+b2), fhalf==1 -> g bf16
  if (fhalf == 0) {
#pragma unroll
    for (int ft = 0; ft < 4; ++ft) {
      int f0 = ft * 16 + q * 4;
      float4 bv = *(const float4*)(b2 + f0);
#pragma unroll
      for (int nt = 0; nt < 2; ++nt) {
        int node = nbase_g + nt * 16 + l15;
        if (node < N) {
          float4 o;
          o.x = acc2[nt][ft][0] + bv.x;
          o.y = acc2[nt][ft][1] + bv.y;
          o.z = acc2[nt][ft][2] + bv.z;
          o.w = acc2[nt][ft][3] + bv.w;
          *(float4*)(out + (size_t)node * M2 + f0) = o;
        }
      }
    }
  } else {
#pragma unroll
    for (int ft = 0; ft < 4; ++ft) {
      int f0 = ft * 16 + q * 4;
#pragma unroll
      for (int nt = 0; nt < 2; ++nt) {
        int node = nbase_g + nt * 16 + l15;
        if (node < N) {
          ushort4 o;
          o.x = f2b(acc2[nt][ft][0]);
          o.y = f2b(acc2[nt][ft][1]);
          o.z = f2b(acc2[nt][ft][2]);
          o.w = f2b(acc2[nt][ft][3]);
          *(ushort4*)(g + (size_t)node * M2 + f0) = o;
        }
      }
    }
  }
}

extern "C" void kernel_launch(void* const* d_in, const int* in_sizes, int n_in,
                              void* d_out, int out_size, void* d_ws, size_t ws_size,
                              hipStream_t stream) {
  const float* x   = (const float*)d_in[0];
  const int*   src = (const int*)d_in[1];
  const int*   dst = (const int*)d_in[2];
  const float* Ws1 = (const float*)d_in[3];
  const float* Wn1 = (const float*)d_in[4];
  const float* b1  = (const float*)d_in[5];
  const float* Ws2 = (const float*)d_in[6];
  const float* Wn2 = (const float*)d_in[7];
  const float* b2  = (const float*)d_in[8];
  float* out = (float*)d_out;

  char* ws = (char*)d_ws;
  size_t off = 0;
  auto alloc = [&](size_t bytes) {
    void* p = ws + off;
    off = (off + bytes + 4095) & ~(size_t)4095;
    return p;
  };
  int* deg       = (int*)alloc((size_t)N_NODES * 4);
  int* row_ptr   = (int*)alloc((size_t)(N_NODES + 1) * 4);
  int* cursor    = (int*)alloc((size_t)N_NODES * 4);
  int* blockSums = (int*)alloc(512 * 4);
  int* csr_src   = (int*)alloc((size_t)N_EDGES * 4);
  unsigned short* xb   = (unsigned short*)alloc((size_t)N_NODES * K_DIM * 2);
  unsigned short* aggb = (unsigned short*)alloc((size_t)N_NODES * K_DIM * 2);
  unsigned short* g    = (unsigned short*)alloc((size_t)N_NODES * M2 * 2);
  unsigned short* Ws1T = (unsigned short*)alloc((size_t)128 * 128 * 2);
  unsigned short* Wn1T = (unsigned short*)alloc((size_t)128 * 128 * 2);
  unsigned short* Ws2T = (unsigned short*)alloc((size_t)64 * 128 * 2);
  unsigned short* Wn2T = (unsigned short*)alloc((size_t)64 * 128 * 2);

  hipMemsetAsync(deg, 0, (size_t)N_NODES * 4, stream);

  // conversions
  {
    long n4 = (long)N_NODES * K_DIM / 4;
    conv_x_kernel<<<(int)((n4 + 255) / 256), 256, 0, stream>>>(x, xb, n4);
  }
  {
    dim3 grid(64, 4);
    conv_wt_kernel<<<grid, 256, 0, stream>>>(Ws1, Wn1, Ws2, Wn2, Ws1T, Wn1T, Ws2T, Wn2T);
  }

  // CSR build
  deg_count<<<(N_EDGES + 255) / 256, 256, 0, stream>>>(dst, deg, N_EDGES);
  scan1<<<SCAN_BLOCKS, 256, 0, stream>>>(deg, row_ptr, blockSums, N_NODES);
  scan2<<<1, 512, 0, stream>>>(blockSums, SCAN_BLOCKS);
  scan3<<<SCAN_BLOCKS, 256, 0, stream>>>(row_ptr, blockSums, cursor, N_NODES, N_EDGES);
  csr_fill<<<(N_EDGES + 255) / 256, 256, 0, stream>>>(src, dst, cursor, csr_src, N_EDGES);

  // layer-1 aggregation
  {
    long t = (long)N_NODES * 16;
    aggregate128<<<(int)((t + 255) / 256), 256, 0, stream>>>(xb, row_ptr, csr_src, aggb, N_NODES);
  }

  // fused layer-1 + layer-2 GEMMs (h1 stays in LDS)
  sage_fused_gemm<<<(N_NODES + 63) / 64, 256, 0, stream>>>(
      xb, aggb, Ws1T, Wn1T, b1, Ws2T, Wn2T, b2, out, g, N_NODES);

  // layer-2 aggregation (adds mean(g) into out)
  {
    long t = (long)N_NODES * 8;
    aggregate64_add<<<(int)((t + 255) / 256), 256, 0, stream>>>(g, row_ptr, csr_src, out, N_NODES);
  }
}